// Round 3
// baseline (203.642 us; speedup 1.0000x reference)
//
#include <hip/hip_runtime.h>

// Problem shape (fixed by reference): N=64, C=1024, H=W=28 -> HW=784
#define HWD 784
#define CD  1024
#define ND  64

#define TILE 16            // positions per block: 64B per channel-row segment
#define NTILE (HWD / TILE) // 49

// ---------------------------------------------------------------------------
// Kernel 1: thr[n,c] = mu * max_{hw} relu(x[n,c,hw] * w[c])
// One wave (64 lanes) per (n,c). 4 waves / 256-thread block.
// ---------------------------------------------------------------------------
__global__ void __launch_bounds__(256) thr_kernel(const float* __restrict__ x,
                                                  const float* __restrict__ w,
                                                  const float* __restrict__ mu_p,
                                                  float* __restrict__ thr) {
    const int wave = threadIdx.x >> 6;
    const int lane = threadIdx.x & 63;
    const int nc = blockIdx.x * 4 + wave;   // 0 .. N*C-1
    const int c = nc & (CD - 1);
    const float wc = w[c];

    const float4* row = reinterpret_cast<const float4*>(x + (size_t)nc * HWD);
    float m = 0.0f;  // relu lower bound is 0, so starting at 0 implements relu
    for (int i = lane; i < HWD / 4; i += 64) {   // 196 float4 per row
        float4 v = row[i];
        m = fmaxf(m, v.x * wc);
        m = fmaxf(m, v.y * wc);
        m = fmaxf(m, v.z * wc);
        m = fmaxf(m, v.w * wc);
    }
    #pragma unroll
    for (int off = 32; off > 0; off >>= 1)
        m = fmaxf(m, __shfl_xor(m, off, 64));

    if (lane == 0)
        thr[nc] = m * mu_p[0];
}

// ---------------------------------------------------------------------------
// Fused kernel 2+3: block = (n, 16-position tile). 64B-aligned segments.
//   Phase A: 64 channel-groups x 4 float4-positions; 16 float4 loads/thread.
//   Phase B: out = x * S (re-read is L2-hot: same 64KB just touched).
// ---------------------------------------------------------------------------
__global__ void __launch_bounds__(256) fused_kernel(const float* __restrict__ x,
                                                    const float* __restrict__ w,
                                                    const float* __restrict__ thr,
                                                    float* __restrict__ out) {
    __shared__ float w_s[CD];
    __shared__ float thr_s[CD];
    __shared__ float4 part4[64][4];
    __shared__ float4 S4[4];

    const int t = threadIdx.x;
    const int n = blockIdx.y;
    const int pos0 = blockIdx.x * TILE;          // byte offset 64*bx: aligned
    const size_t nbase = (size_t)n * CD * HWD;

    // stage w and thr[n,:] in LDS
    const float* thr_n = thr + n * CD;
    #pragma unroll
    for (int i = 0; i < CD / 256; ++i) {
        w_s[t + 256 * i]   = w[t + 256 * i];
        thr_s[t + 256 * i] = thr_n[t + 256 * i];
    }
    __syncthreads();

    // ---- Phase A: dropped-sum over channels ----
    const int g = t >> 2;                        // 0..63 channel group
    const int q = t & 3;                         // float4 slot in tile
    const float* base = x + nbase + pos0 + q * 4;
    float4 s = {0.f, 0.f, 0.f, 0.f};
    #pragma unroll 4
    for (int k = 0; k < CD / 64; ++k) {          // 16 iterations
        const int c = g + (k << 6);
        float4 v = *reinterpret_cast<const float4*>(base + (size_t)c * HWD);
        const float wc = w_s[c], tc = thr_s[c];
        float cam;
        cam = fmaxf(v.x * wc, 0.f); s.x += (cam > tc) ? 0.f : cam;
        cam = fmaxf(v.y * wc, 0.f); s.y += (cam > tc) ? 0.f : cam;
        cam = fmaxf(v.z * wc, 0.f); s.z += (cam > tc) ? 0.f : cam;
        cam = fmaxf(v.w * wc, 0.f); s.w += (cam > tc) ? 0.f : cam;
    }
    part4[g][q] = s;
    __syncthreads();

    // tree-reduce over the 64 channel groups
    #pragma unroll
    for (int stp = 32; stp >= 1; stp >>= 1) {
        if (g < stp) {
            float4 a = part4[g][q];
            float4 b = part4[g + stp][q];
            a.x += b.x; a.y += b.y; a.z += b.z; a.w += b.w;
            part4[g][q] = a;
        }
        __syncthreads();
    }
    if (t < 4) S4[t] = part4[0][t];
    __syncthreads();

    // ---- Phase B: out = x * S ----
    const float4 sv = S4[q];                     // j & 3 == q for all j below
    for (int j = t; j < CD * 4; j += 256) {      // 16 iterations
        const int c = j >> 2;
        const size_t idx = nbase + (size_t)c * HWD + pos0 + (j & 3) * 4;
        float4 xv = *reinterpret_cast<const float4*>(x + idx);
        float4 o;
        o.x = xv.x * sv.x;
        o.y = xv.y * sv.y;
        o.z = xv.z * sv.z;
        o.w = xv.w * sv.w;
        *reinterpret_cast<float4*>(out + idx) = o;
    }
}

extern "C" void kernel_launch(void* const* d_in, const int* in_sizes, int n_in,
                              void* d_out, int out_size, void* d_ws, size_t ws_size,
                              hipStream_t stream) {
    const float* x  = (const float*)d_in[0];   // [N, C, H, W] f32
    const float* w  = (const float*)d_in[1];   // [C] f32
    const float* mu = (const float*)d_in[2];   // scalar (1-elem array)
    float* out = (float*)d_out;

    float* thr = (float*)d_ws;                 // N*C floats (256 KB scratch)

    // Kernel 1: N*C = 65536 waves, 4 per block -> 16384 blocks
    thr_kernel<<<(ND * CD) / 4, 256, 0, stream>>>(x, w, mu, thr);

    // Fused kernel: 49 x 64 = 3136 blocks
    dim3 g2(NTILE, ND);
    fused_kernel<<<g2, 256, 0, stream>>>(x, w, thr, out);
}

// Round 4
// 142.360 us; speedup vs baseline: 1.4305x; 1.4305x over previous
//
#include <hip/hip_runtime.h>

// Problem shape (fixed by reference): N=64, C=1024, H=W=28 -> HW=784
#define HWD 784
#define CD  1024
#define ND  64

#define TILE 16            // positions per block: 64B per channel-row segment
#define NTILE (HWD / TILE) // 49

// ---------------------------------------------------------------------------
// Kernel 1: thr[n,c] = mu * max_{hw} relu(x[n,c,hw] * w[c])
// One wave (64 lanes) per (n,c). 4 waves / 256-thread block.
// ~29us measured = 7.1 TB/s effective on its 205MB read; near peak.
// ---------------------------------------------------------------------------
__global__ void __launch_bounds__(256) thr_kernel(const float* __restrict__ x,
                                                  const float* __restrict__ w,
                                                  const float* __restrict__ mu_p,
                                                  float* __restrict__ thr) {
    const int wave = threadIdx.x >> 6;
    const int lane = threadIdx.x & 63;
    const int nc = blockIdx.x * 4 + wave;   // 0 .. N*C-1
    const int c = nc & (CD - 1);
    const float wc = w[c];

    const float4* row = reinterpret_cast<const float4*>(x + (size_t)nc * HWD);
    float m = 0.0f;  // relu lower bound is 0, so starting at 0 implements relu
    for (int i = lane; i < HWD / 4; i += 64) {   // 196 float4 per row
        float4 v = row[i];
        m = fmaxf(m, v.x * wc);
        m = fmaxf(m, v.y * wc);
        m = fmaxf(m, v.z * wc);
        m = fmaxf(m, v.w * wc);
    }
    #pragma unroll
    for (int off = 32; off > 0; off >>= 1)
        m = fmaxf(m, __shfl_xor(m, off, 64));

    if (lane == 0)
        thr[nc] = m * mu_p[0];
}

// ---------------------------------------------------------------------------
// Fused kernel 2+3: block = (n, 16-position tile), x-tile held in REGISTERS.
//   Phase A: each thread loads 16 float4s (its 16 channel rows), computes
//            dropped-sum partial; keeps the loads in VGPRs.
//   Reduce:  intra-wave shfl_xor over the 16 lane-local channel groups,
//            then 4 wave-partials summed via LDS (one barrier pair).
//   Phase B: multiply held registers by S, store. x is read exactly ONCE.
// ---------------------------------------------------------------------------
__global__ void __launch_bounds__(256) fused_kernel(const float* __restrict__ x,
                                                    const float* __restrict__ w,
                                                    const float* __restrict__ thr,
                                                    float* __restrict__ out) {
    __shared__ float w_s[CD];
    __shared__ float thr_s[CD];
    __shared__ float4 partw[4][4];   // [wave][q]
    __shared__ float4 S4[4];

    const int t = threadIdx.x;
    const int wave = t >> 6;
    const int lane = t & 63;
    const int g = t >> 2;                        // 0..63 channel group
    const int q = t & 3;                         // float4 slot in tile
    const int n = blockIdx.y;
    const int pos0 = blockIdx.x * TILE;          // byte offset 64*bx: aligned
    const size_t nbase = (size_t)n * CD * HWD;

    // stage w and thr[n,:] in LDS
    const float* thr_n = thr + n * CD;
    #pragma unroll
    for (int i = 0; i < CD / 256; ++i) {
        w_s[t + 256 * i]   = w[t + 256 * i];
        thr_s[t + 256 * i] = thr_n[t + 256 * i];
    }

    // ---- Phase A: load 16 float4s into registers ----
    const float* base = x + nbase + pos0 + q * 4;
    float4 xv[16];
    #pragma unroll
    for (int k = 0; k < 16; ++k)
        xv[k] = *reinterpret_cast<const float4*>(base + (size_t)(g + (k << 6)) * HWD);

    __syncthreads();   // w_s/thr_s ready (overlapped with the 16 loads)

    float4 s = {0.f, 0.f, 0.f, 0.f};
    #pragma unroll
    for (int k = 0; k < 16; ++k) {
        const int c = g + (k << 6);
        const float wc = w_s[c], tc = thr_s[c];
        float cam;
        cam = fmaxf(xv[k].x * wc, 0.f); s.x += (cam > tc) ? 0.f : cam;
        cam = fmaxf(xv[k].y * wc, 0.f); s.y += (cam > tc) ? 0.f : cam;
        cam = fmaxf(xv[k].z * wc, 0.f); s.z += (cam > tc) ? 0.f : cam;
        cam = fmaxf(xv[k].w * wc, 0.f); s.w += (cam > tc) ? 0.f : cam;
    }

    // intra-wave reduce over the 16 lane-local g values (lanes with equal q)
    #pragma unroll
    for (int off = 4; off <= 32; off <<= 1) {
        s.x += __shfl_xor(s.x, off, 64);
        s.y += __shfl_xor(s.y, off, 64);
        s.z += __shfl_xor(s.z, off, 64);
        s.w += __shfl_xor(s.w, off, 64);
    }
    if (lane < 4) partw[wave][lane] = s;   // lane == q for lanes 0..3
    __syncthreads();
    if (t < 4) {
        float4 a = partw[0][t], b = partw[1][t], c4 = partw[2][t], d = partw[3][t];
        a.x += b.x + c4.x + d.x;
        a.y += b.y + c4.y + d.y;
        a.z += b.z + c4.z + d.z;
        a.w += b.w + c4.w + d.w;
        S4[t] = a;
    }
    __syncthreads();

    // ---- Phase B: out = x * S from registers (no global re-read) ----
    const float4 sv = S4[q];
    float* obase = out + nbase + pos0 + q * 4;
    #pragma unroll
    for (int k = 0; k < 16; ++k) {
        float4 o;
        o.x = xv[k].x * sv.x;
        o.y = xv[k].y * sv.y;
        o.z = xv[k].z * sv.z;
        o.w = xv[k].w * sv.w;
        *reinterpret_cast<float4*>(obase + (size_t)(g + (k << 6)) * HWD) = o;
    }
}

extern "C" void kernel_launch(void* const* d_in, const int* in_sizes, int n_in,
                              void* d_out, int out_size, void* d_ws, size_t ws_size,
                              hipStream_t stream) {
    const float* x  = (const float*)d_in[0];   // [N, C, H, W] f32
    const float* w  = (const float*)d_in[1];   // [C] f32
    const float* mu = (const float*)d_in[2];   // scalar (1-elem array)
    float* out = (float*)d_out;

    float* thr = (float*)d_ws;                 // N*C floats (256 KB scratch)

    // Kernel 1: N*C = 65536 waves, 4 per block -> 16384 blocks
    thr_kernel<<<(ND * CD) / 4, 256, 0, stream>>>(x, w, mu, thr);

    // Fused kernel: 49 x 64 = 3136 blocks
    dim3 g2(NTILE, ND);
    fused_kernel<<<g2, 256, 0, stream>>>(x, w, thr, out);
}

// Round 5
// 124.980 us; speedup vs baseline: 1.6294x; 1.1391x over previous
//
#include <hip/hip_runtime.h>

// Problem shape (fixed by reference): N=64, C=1024, H=W=28 -> HW=784
#define HWD 784
#define CD  1024
#define ND  64

#define TILE 16            // positions per block: 64B per channel-row segment
#define NTILE (HWD / TILE) // 49

typedef float f32x4 __attribute__((ext_vector_type(4)));

// ---------------------------------------------------------------------------
// Kernel 1: thr[n,c] = mu * max_{hw} relu(x[n,c,hw] * w[c])
// One wave (64 lanes) per (n,c). 4 waves / 256-thread block.
// ~32us = 6.4 TB/s on its 205MB cold read; near HBM peak. Side effect we
// rely on: leaves all of x resident in the 256MB Infinity Cache.
// ---------------------------------------------------------------------------
__global__ void __launch_bounds__(256) thr_kernel(const float* __restrict__ x,
                                                  const float* __restrict__ w,
                                                  const float* __restrict__ mu_p,
                                                  float* __restrict__ thr) {
    const int wave = threadIdx.x >> 6;
    const int lane = threadIdx.x & 63;
    const int nc = blockIdx.x * 4 + wave;   // 0 .. N*C-1
    const int c = nc & (CD - 1);
    const float wc = w[c];

    const float4* row = reinterpret_cast<const float4*>(x + (size_t)nc * HWD);
    float m = 0.0f;  // relu lower bound is 0, so starting at 0 implements relu
    for (int i = lane; i < HWD / 4; i += 64) {   // 196 float4 per row
        float4 v = row[i];
        m = fmaxf(m, v.x * wc);
        m = fmaxf(m, v.y * wc);
        m = fmaxf(m, v.z * wc);
        m = fmaxf(m, v.w * wc);
    }
    #pragma unroll
    for (int off = 32; off > 0; off >>= 1)
        m = fmaxf(m, __shfl_xor(m, off, 64));

    if (lane == 0)
        thr[nc] = m * mu_p[0];
}

// ---------------------------------------------------------------------------
// Fused kernel 2+3: block = (n, 16-position tile), x-tile held in REGISTERS.
//   Phase A: each thread loads 16 float4s (its 16 channel rows) — these
//            should be L3 hits (x just streamed by thr_kernel).
//   Reduce:  intra-wave shfl_xor + one LDS step.
//   Phase B: multiply held registers by S; NON-TEMPORAL store so the out
//            stream does not evict x from L3 ahead of the read pointer.
// ---------------------------------------------------------------------------
__global__ void __launch_bounds__(256) fused_kernel(const float* __restrict__ x,
                                                    const float* __restrict__ w,
                                                    const float* __restrict__ thr,
                                                    float* __restrict__ out) {
    __shared__ float w_s[CD];
    __shared__ float thr_s[CD];
    __shared__ float4 partw[4][4];   // [wave][q]
    __shared__ float4 S4[4];

    const int t = threadIdx.x;
    const int wave = t >> 6;
    const int lane = t & 63;
    const int g = t >> 2;                        // 0..63 channel group
    const int q = t & 3;                         // float4 slot in tile
    const int n = blockIdx.y;
    const int pos0 = blockIdx.x * TILE;          // byte offset 64*bx: aligned
    const size_t nbase = (size_t)n * CD * HWD;

    // stage w and thr[n,:] in LDS
    const float* thr_n = thr + n * CD;
    #pragma unroll
    for (int i = 0; i < CD / 256; ++i) {
        w_s[t + 256 * i]   = w[t + 256 * i];
        thr_s[t + 256 * i] = thr_n[t + 256 * i];
    }

    // ---- Phase A: load 16 float4s into registers ----
    const float* base = x + nbase + pos0 + q * 4;
    float4 xv[16];
    #pragma unroll
    for (int k = 0; k < 16; ++k)
        xv[k] = *reinterpret_cast<const float4*>(base + (size_t)(g + (k << 6)) * HWD);

    __syncthreads();   // w_s/thr_s ready (overlapped with the 16 loads)

    float4 s = {0.f, 0.f, 0.f, 0.f};
    #pragma unroll
    for (int k = 0; k < 16; ++k) {
        const int c = g + (k << 6);
        const float wc = w_s[c], tc = thr_s[c];
        float cam;
        cam = fmaxf(xv[k].x * wc, 0.f); s.x += (cam > tc) ? 0.f : cam;
        cam = fmaxf(xv[k].y * wc, 0.f); s.y += (cam > tc) ? 0.f : cam;
        cam = fmaxf(xv[k].z * wc, 0.f); s.z += (cam > tc) ? 0.f : cam;
        cam = fmaxf(xv[k].w * wc, 0.f); s.w += (cam > tc) ? 0.f : cam;
    }

    // intra-wave reduce over the 16 lane-local g values (lanes with equal q)
    #pragma unroll
    for (int off = 4; off <= 32; off <<= 1) {
        s.x += __shfl_xor(s.x, off, 64);
        s.y += __shfl_xor(s.y, off, 64);
        s.z += __shfl_xor(s.z, off, 64);
        s.w += __shfl_xor(s.w, off, 64);
    }
    if (lane < 4) partw[wave][lane] = s;   // lane == q for lanes 0..3
    __syncthreads();
    if (t < 4) {
        float4 a = partw[0][t], b = partw[1][t], c4 = partw[2][t], d = partw[3][t];
        a.x += b.x + c4.x + d.x;
        a.y += b.y + c4.y + d.y;
        a.z += b.z + c4.z + d.z;
        a.w += b.w + c4.w + d.w;
        S4[t] = a;
    }
    __syncthreads();

    // ---- Phase B: out = x * S from registers, non-temporal stores ----
    const float4 sv = S4[q];
    float* obase = out + nbase + pos0 + q * 4;
    #pragma unroll
    for (int k = 0; k < 16; ++k) {
        float4 o;
        o.x = xv[k].x * sv.x;
        o.y = xv[k].y * sv.y;
        o.z = xv[k].z * sv.z;
        o.w = xv[k].w * sv.w;
        __builtin_nontemporal_store(
            *reinterpret_cast<const f32x4*>(&o),
            reinterpret_cast<f32x4*>(obase + (size_t)(g + (k << 6)) * HWD));
    }
}

extern "C" void kernel_launch(void* const* d_in, const int* in_sizes, int n_in,
                              void* d_out, int out_size, void* d_ws, size_t ws_size,
                              hipStream_t stream) {
    const float* x  = (const float*)d_in[0];   // [N, C, H, W] f32
    const float* w  = (const float*)d_in[1];   // [C] f32
    const float* mu = (const float*)d_in[2];   // scalar (1-elem array)
    float* out = (float*)d_out;

    float* thr = (float*)d_ws;                 // N*C floats (256 KB scratch)

    // Kernel 1: N*C = 65536 waves, 4 per block -> 16384 blocks
    thr_kernel<<<(ND * CD) / 4, 256, 0, stream>>>(x, w, mu, thr);

    // Fused kernel: 49 x 64 = 3136 blocks
    dim3 g2(NTILE, ND);
    fused_kernel<<<g2, 256, 0, stream>>>(x, w, thr, out);
}